// Round 6
// baseline (35365.494 us; speedup 1.0000x reference)
//
#include <hip/hip_runtime.h>
#include <cstdint>
#include <cstddef>

// ---------------------------------------------------------------------------
// TaggingFNNDecoder round 6 (= round 5 + macro-hygiene compile fix).
// r5 failed to compile: FMA4's parameter was named `w`, so `(a).w` inside the
// macro body got token-substituted into `(a).w0` etc. Params renamed W_/A_.
// Design (from r5):
//  * 8 named scalar accumulators/thread: thread (bb in 32, kg8 in 8) owns the
//    8 gate rows of its block for ONE batch over a 1/8 k-slice; 3-stage
//    in-wave shfl_xor butterfly reduces k (7 shuffles).
//  * All cross-block state via inline-asm global_load/store dwordx4 sc0 sc1
//    (coalesced 16B/lane, LLC = coherence point, zero cache maintenance).
//    Fences = s_waitcnt vmcnt(N) asm that re-defines the loaded regs.
//  * h-state prefetch for P1(t+1) issued in P3(t) (hidden behind barrier).
//  * Output head: 128 blocks compute k-partial logits (W_out pre-transposed
//    into ws for coalesced reads); 32 blocks combine+softmax early in the
//    next P1 behind a 32-producer flag (normally zero wait).
//  * Barriers: r4's proven LLC-flag barrier.
// ---------------------------------------------------------------------------

#define Bz   32
#define Tz   256
#define Dz   1024
#define Hz   512
#define NK   128
#define IN0  1152
#define NBLK 256
#define BH   16384

typedef float vf4 __attribute__((ext_vector_type(4)));

#define R8(OP) OP(0) OP(1) OP(2) OP(3) OP(4) OP(5) OP(6) OP(7)

__device__ __forceinline__ void ldsc4(vf4& d, const float* p) {
  asm volatile("global_load_dwordx4 %0, %1, off sc0 sc1" : "=v"(d) : "v"(p));
}
__device__ __forceinline__ void ldsc1(float& d, const float* p) {
  asm volatile("global_load_dword %0, %1, off sc0 sc1" : "=v"(d) : "v"(p));
}
__device__ __forceinline__ void stsc1(float* p, float v) {
  asm volatile("global_store_dword %0, %1, off sc0 sc1" :: "v"(p), "v"(v) : "memory");
}

#define FENCE8(c, a0,a1,a2,a3,a4,a5,a6,a7) \
  asm volatile("s_waitcnt vmcnt(" #c ")" : "+v"(a0),"+v"(a1),"+v"(a2),"+v"(a3), \
               "+v"(a4),"+v"(a5),"+v"(a6),"+v"(a7) :: "memory")
#define FENCE4(a0,a1,a2,a3) \
  asm volatile("s_waitcnt vmcnt(0)" : "+v"(a0),"+v"(a1),"+v"(a2),"+v"(a3) :: "memory")

// NOTE: parameter names must not collide with vector member names x/y/z/w.
#define FMA4(acc, W_, A_) \
  acc = fmaf((W_).x,(A_).x, fmaf((W_).y,(A_).y, fmaf((W_).z,(A_).z, fmaf((W_).w,(A_).w,(acc)))))

__device__ __forceinline__ float sigf(float x) { return 1.0f / (1.0f + expf(-x)); }
__device__ __forceinline__ int rowg(int r, int j0) { return (r >> 1) * Hz + j0 + (r & 1); }

// ---------------- grid barrier (r4, proven) -------------------------------
__device__ __forceinline__ void gbar(unsigned int* bar, unsigned int g) {
  asm volatile("s_waitcnt vmcnt(0)" ::: "memory");
  __syncthreads();
  if (threadIdx.x == 0)
    __hip_atomic_store(bar + blockIdx.x * 16, g,
                       __ATOMIC_RELAXED, __HIP_MEMORY_SCOPE_SYSTEM);
  if (blockIdx.x == NBLK - 1) {
    unsigned int* ws = bar + threadIdx.x * 16;
    while (__hip_atomic_load(ws, __ATOMIC_RELAXED, __HIP_MEMORY_SCOPE_SYSTEM) < g)
      __builtin_amdgcn_s_sleep(1);
    __syncthreads();
    if (threadIdx.x == 0) {
      asm volatile("s_waitcnt vmcnt(0)" ::: "memory");
      __hip_atomic_store(bar + NBLK * 16, g,
                         __ATOMIC_RELAXED, __HIP_MEMORY_SCOPE_SYSTEM);
    }
  } else if (threadIdx.x == 0) {
    while (__hip_atomic_load(bar + NBLK * 16, __ATOMIC_RELAXED,
                             __HIP_MEMORY_SCOPE_SYSTEM) < g)
      __builtin_amdgcn_s_sleep(1);
  }
  __syncthreads();
}

// 3-stage value-halving butterfly over kg8; lane's A0 = full sum of row
// rev3(kg8). Writes gbuf[row][bb] (+bias).
#define REDUCE_STORE(BIAS) { \
  { const bool hi = (kg8 & 1) != 0; \
    float s0 = hi?A0:A4, s1 = hi?A1:A5, s2 = hi?A2:A6, s3 = hi?A3:A7; \
    float k0 = hi?A4:A0, k1 = hi?A5:A1, k2 = hi?A6:A2, k3 = hi?A7:A3; \
    A0 = k0 + __shfl_xor(s0, 1, 64); A1 = k1 + __shfl_xor(s1, 1, 64); \
    A2 = k2 + __shfl_xor(s2, 1, 64); A3 = k3 + __shfl_xor(s3, 1, 64); } \
  { const bool hi = (kg8 & 2) != 0; \
    float s0 = hi?A0:A2, s1 = hi?A1:A3; \
    float k0 = hi?A2:A0, k1 = hi?A3:A1; \
    A0 = k0 + __shfl_xor(s0, 2, 64); A1 = k1 + __shfl_xor(s1, 2, 64); } \
  { const bool hi = (kg8 & 4) != 0; \
    float s0 = hi?A0:A1; float k0 = hi?A1:A0; \
    A0 = k0 + __shfl_xor(s0, 4, 64); } \
  const int rr = ((kg8 & 1) << 2) | (kg8 & 2) | ((kg8 & 4) >> 2); \
  gbuf[rr][bb] = A0 + BIAS[rr]; }

#define GATES(CREG, HDST) \
  __syncthreads(); \
  if (tid < 64) { \
    float gi = gbuf[0 + cj][cb], gf = gbuf[2 + cj][cb]; \
    float gg = gbuf[4 + cj][cb], go = gbuf[6 + cj][cb]; \
    CREG = sigf(gf) * CREG + sigf(gi) * tanhf(gg); \
    stsc1(HDST + cb * Hz + jc, sigf(go) * tanhf(CREG)); \
  }

// ---------------- combine partials + softmax (blocks 0..31, all threads) --
__device__ void sm_combine(int tprev, int bb, const float* __restrict__ partials,
                           const float* __restrict__ b_out, const float* __restrict__ mask,
                           float* __restrict__ smg, float* __restrict__ out,
                           float* wred, unsigned int* flag) {
  const int tid = threadIdx.x;
  const int n = tid & 127;
  float logit = 0.0f;
  if (tid < 128) {
    const float* pp = partials + bb * 512 + n;
    float p0, p1, p2, p3;
    ldsc1(p0, pp); ldsc1(p1, pp + 128); ldsc1(p2, pp + 256); ldsc1(p3, pp + 384);
    asm volatile("s_waitcnt vmcnt(0)" : "+v"(p0), "+v"(p1), "+v"(p2), "+v"(p3) :: "memory");
    logit = p0 + p1 + p2 + p3 + b_out[n];
  }
  float m = logit;
  #pragma unroll
  for (int off = 32; off >= 1; off >>= 1) m = fmaxf(m, __shfl_xor(m, off));
  if ((tid & 63) == 0 && tid < 128) wred[tid >> 6] = m;
  __syncthreads();
  float M = fmaxf(wred[0], wred[1]);
  float e = (tid < 128) ? expf(logit - M) : 0.0f;
  float s = e;
  #pragma unroll
  for (int off = 32; off >= 1; off >>= 1) s += __shfl_xor(s, off);
  if ((tid & 63) == 0 && tid < 128) wred[2 + (tid >> 6)] = s;
  __syncthreads();
  float S = wred[2] + wred[3];
  if (tid < 128) stsc1(smg + bb * NK + n, e / S);
  asm volatile("s_waitcnt vmcnt(0)" ::: "memory");
  __syncthreads();
  if (tid == 0)   // release sm for consumers (stores drained above)
    __hip_atomic_fetch_add(flag, 1u, __ATOMIC_RELAXED, __HIP_MEMORY_SCOPE_SYSTEM);
  // masked output softmax (off critical path)
  float mk = (tid < 128 && tprev >= 0) ? mask[bb * Tz + tprev] : 1.0f;
  float lm = (tid < 128) ? (logit + (1.0f - mk) * (-1e32f)) : -3.0e38f;
  float m2 = lm;
  #pragma unroll
  for (int off = 32; off >= 1; off >>= 1) m2 = fmaxf(m2, __shfl_xor(m2, off));
  if ((tid & 63) == 0 && tid < 128) wred[4 + (tid >> 6)] = m2;
  __syncthreads();
  float M2 = fmaxf(wred[4], wred[5]);
  float e2 = (tid < 128) ? expf(lm - M2) : 0.0f;
  float s2 = e2;
  #pragma unroll
  for (int off = 32; off >= 1; off >>= 1) s2 += __shfl_xor(s2, off);
  if ((tid & 63) == 0 && tid < 128) wred[6 + (tid >> 6)] = s2;
  __syncthreads();
  float S2 = wred[6] + wred[7];
  if (tprev >= 0 && tid < 128)
    out[((size_t)bb * Tz + tprev) * NK + n] = e2 / S2;
}

// ---------------- W_out transpose (once per launch) -----------------------
__global__ void __launch_bounds__(256)
wt_kernel(const float* __restrict__ W_out, float* __restrict__ Wt) {
  int idx = blockIdx.x * 256 + threadIdx.x;       // 64K elements
  int n = idx & 127, k = idx >> 7;
  Wt[(size_t)k * NK + n] = W_out[(size_t)n * Hz + k];
}

// ---------------- the persistent kernel -----------------------------------
__global__ void __launch_bounds__(256, 2)
seq_kernel(const float* __restrict__ hiddens,
           const float* __restrict__ h_t, const float* __restrict__ c_t,
           const float* __restrict__ mask,
           const float* __restrict__ b_out,
           const float* __restrict__ W_ih0, const float* __restrict__ W_hh0,
           const float* __restrict__ b_ih0, const float* __restrict__ b_hh0,
           const float* __restrict__ W_ih1, const float* __restrict__ W_hh1,
           const float* __restrict__ b_ih1, const float* __restrict__ b_hh1,
           const float* __restrict__ Wt, float* __restrict__ out,
           float* __restrict__ h1g, float* __restrict__ h2g,
           float* __restrict__ smg, float* __restrict__ partials,
           unsigned int* bar) {
  __shared__ float gbuf[8][32];
  __shared__ float wred[8];
  __shared__ float biasA[8], biasB[8];
  __shared__ float hstage[128];
  __shared__ float cpart[128][2];

  const int tid = threadIdx.x;
  const int bid = blockIdx.x;
  const int bb  = tid >> 3;          // batch (0..31)
  const int kg8 = tid & 7;           // k-slice (0..7)
  const int j0  = 2 * bid;
  unsigned int* flag = bar + NBLK * 16 + 16;

  if (tid < 8) {
    const int row = rowg(tid, j0);
    biasA[tid] = b_ih0[row] + b_hh0[row];
    biasB[tid] = b_ih1[row] + b_hh1[row];
  }

  // weight slice base pointers (block-uniform base + lane k-offset)
  #define DWX(r) const float* wx##r = W_ih0 + (size_t)rowg(r, j0) * IN0 + (kg8 << 7);
  R8(DWX)
  #define DWH(r) const float* wh##r = W_hh0 + (size_t)rowg(r, j0) * Hz + (kg8 << 6);
  R8(DWH)
  #define DWS(r) const float* ws##r = W_ih0 + (size_t)rowg(r, j0) * IN0 + 1024 + (kg8 << 4);
  R8(DWS)
  #define DWI(r) const float* wi##r = W_ih1 + (size_t)rowg(r, j0) * Hz + (kg8 << 6);
  R8(DWI)
  #define DWG(r) const float* wg##r = W_hh1 + (size_t)rowg(r, j0) * Hz + (kg8 << 6);
  R8(DWG)

  // cell state registers (threads 0..63) for all 256 steps
  const int cb = tid & 31, cj = (tid >> 5) & 1, jc = j0 + cj;
  float c1r = 0.0f, c2r = 0.0f;
  if (tid < 64) {
    c1r = c_t[cb * Hz + jc];
    c2r = c_t[BH + cb * Hz + jc];
    stsc1(h1g + BH + cb * Hz + jc, h_t[cb * Hz + jc]);       // parity-1 init
    stsc1(h2g + BH + cb * Hz + jc, h_t[BH + cb * Hz + jc]);
  }

  // initial output-head partials from hiddens[:,0,:512] (cached source)
  if (bid < 128) {
    const int bcp = bid >> 2, kq = bid & 3;
    if (tid < 32)
      *(vf4*)&hstage[tid << 2] =
        *(const vf4*)(hiddens + (size_t)bcp * Tz * Dz + (kq << 7) + (tid << 2));
    __syncthreads();
    const int n = tid & 127, ks = tid >> 7;
    float p = 0.0f;
    const float* wt = Wt + (size_t)((kq << 7) + (ks << 6)) * NK + n;
    #pragma unroll 8
    for (int k = 0; k < 64; ++k)
      p = fmaf(wt[k * NK], hstage[(ks << 6) + k], p);
    cpart[n][ks] = p;
    __syncthreads();
    if (tid < 128)
      stsc1(partials + (size_t)bcp * 512 + (kq << 7) + n, cpart[n][0] + cpart[n][1]);
  }

  unsigned int g = 1;
  gbar(bar, g); ++g;

  // prefetch h1prev slice for t=0 (h_t staged at parity 1)
  vf4 hh[16];
  #pragma unroll
  for (int i = 0; i < 16; ++i)
    ldsc4(hh[i], h1g + BH + (size_t)bb * Hz + (kg8 << 6) + (i << 2));

  for (int t = 0; t < Tz; ++t) {
    float* h1cur = h1g + (t & 1) * BH;
    const float* h2prev = h2g + ((t + 1) & 1) * BH;
    float* h2cur = h2g + (t & 1) * BH;

    // ================= P1: layer-0 over [h1prev | x_t | sm] ==============
    {
      if (bid < 32)   // produce sm(t-1) early; consumers wait on flag below
        sm_combine(t - 1, bid, partials, b_out, mask, smg, out, wred, flag);

      float A0=0.f,A1=0.f,A2=0.f,A3=0.f,A4=0.f,A5=0.f,A6=0.f,A7=0.f;
      // X phase (cached acts + weights), overlaps prefetched-H latency
      const float* xp = hiddens + ((size_t)bb * Tz + t) * Dz + (kg8 << 7);
      #pragma unroll 4
      for (int ki = 0; ki < 128; ki += 4) {
        vf4 ax = *(const vf4*)(xp + ki);
        #define XF(r) { vf4 wv = *(const vf4*)(wx##r + ki); FMA4(A##r, wv, ax); }
        R8(XF)
        #undef XF
      }
      // H phase: consume prefetched h1prev
      FENCE8(0, hh[0],hh[1],hh[2],hh[3],hh[4],hh[5],hh[6],hh[7]);
      FENCE8(0, hh[8],hh[9],hh[10],hh[11],hh[12],hh[13],hh[14],hh[15]);
      #pragma unroll
      for (int i = 0; i < 16; ++i) {
        vf4 av = hh[i];
        #define HF(r) { vf4 wv = *(const vf4*)(wh##r + (i << 2)); FMA4(A##r, wv, av); }
        R8(HF)
        #undef HF
      }
      // S phase: wait for the 32 softmax producers, then sm slice
      if (tid == 0) {
        const unsigned int need = 32u * (unsigned int)(t + 1);
        while (__hip_atomic_load(flag, __ATOMIC_RELAXED, __HIP_MEMORY_SCOPE_SYSTEM) < need)
          __builtin_amdgcn_s_sleep(1);
      }
      __syncthreads();
      vf4 s0, s1, s2, s3;
      const float* sp = smg + bb * NK + (kg8 << 4);
      ldsc4(s0, sp); ldsc4(s1, sp + 4); ldsc4(s2, sp + 8); ldsc4(s3, sp + 12);
      FENCE4(s0, s1, s2, s3);
      #define SF(r) { vf4 w0v=*(const vf4*)(ws##r); vf4 w1v=*(const vf4*)(ws##r+4); \
                      vf4 w2v=*(const vf4*)(ws##r+8); vf4 w3v=*(const vf4*)(ws##r+12); \
                      FMA4(A##r,w0v,s0); FMA4(A##r,w1v,s1); FMA4(A##r,w2v,s2); FMA4(A##r,w3v,s3); }
      R8(SF)
      #undef SF
      REDUCE_STORE(biasA)
      GATES(c1r, h1cur)
    }
    gbar(bar, g); ++g;

    // ================= P2: layer-1 over [h1cur | h2prev] =================
    {
      vf4 hb[16], hc[16];
      #pragma unroll
      for (int i = 0; i < 16; ++i)
        ldsc4(hb[i], h1cur + (size_t)bb * Hz + (kg8 << 6) + (i << 2));
      #pragma unroll
      for (int i = 0; i < 16; ++i)
        ldsc4(hc[i], h2prev + (size_t)bb * Hz + (kg8 << 6) + (i << 2));
      float A0=0.f,A1=0.f,A2=0.f,A3=0.f,A4=0.f,A5=0.f,A6=0.f,A7=0.f;
      FENCE8(16, hb[0],hb[1],hb[2],hb[3],hb[4],hb[5],hb[6],hb[7]);
      FENCE8(16, hb[8],hb[9],hb[10],hb[11],hb[12],hb[13],hb[14],hb[15]);
      #pragma unroll
      for (int i = 0; i < 16; ++i) {
        vf4 av = hb[i];
        #define IF_(r) { vf4 wv = *(const vf4*)(wi##r + (i << 2)); FMA4(A##r, wv, av); }
        R8(IF_)
        #undef IF_
      }
      FENCE8(0, hc[0],hc[1],hc[2],hc[3],hc[4],hc[5],hc[6],hc[7]);
      FENCE8(0, hc[8],hc[9],hc[10],hc[11],hc[12],hc[13],hc[14],hc[15]);
      #pragma unroll
      for (int i = 0; i < 16; ++i) {
        vf4 av = hc[i];
        #define GF(r) { vf4 wv = *(const vf4*)(wg##r + (i << 2)); FMA4(A##r, wv, av); }
        R8(GF)
        #undef GF
      }
      REDUCE_STORE(biasB)
      GATES(c2r, h2cur)
    }
    gbar(bar, g); ++g;

    // ================= P3: prefetch + output-head partials ===============
    {
      // prefetch h1prev(t+1) = h1cur(t) — final since bar1
      #pragma unroll
      for (int i = 0; i < 16; ++i)
        ldsc4(hh[i], h1cur + (size_t)bb * Hz + (kg8 << 6) + (i << 2));
      if (bid < 128) {
        const int bcp = bid >> 2, kq = bid & 3;
        if (tid < 32) {
          vf4 v;
          ldsc4(v, h2cur + (size_t)bcp * Hz + (kq << 7) + (tid << 2));
          asm volatile("s_waitcnt vmcnt(16)" : "+v"(v) :: "memory");
          *(vf4*)&hstage[tid << 2] = v;
        }
        __syncthreads();
        const int n = tid & 127, ks = tid >> 7;
        float p = 0.0f;
        const float* wt = Wt + (size_t)((kq << 7) + (ks << 6)) * NK + n;
        #pragma unroll 8
        for (int k = 0; k < 64; ++k)
          p = fmaf(wt[k * NK], hstage[(ks << 6) + k], p);
        cpart[n][ks] = p;
        __syncthreads();
        if (tid < 128)
          stsc1(partials + (size_t)bcp * 512 + (kq << 7) + n, cpart[n][0] + cpart[n][1]);
      }
    }
    gbar(bar, g); ++g;
  }

  // final output column t=255
  if (bid < 32)
    sm_combine(Tz - 1, bid, partials, b_out, mask, smg, out, wred, flag);
}

// ---------------------------------------------------------------------------
extern "C" void kernel_launch(void* const* d_in, const int* in_sizes, int n_in,
                              void* d_out, int out_size, void* d_ws, size_t ws_size,
                              hipStream_t stream) {
  (void)in_sizes; (void)n_in; (void)out_size; (void)ws_size;
  const float* hiddens = (const float*)d_in[0];
  const float* h_t     = (const float*)d_in[1];
  const float* c_t     = (const float*)d_in[2];
  const float* mask    = (const float*)d_in[3];
  const float* W_out   = (const float*)d_in[4];
  const float* b_out   = (const float*)d_in[5];
  const float* W_ih0   = (const float*)d_in[6];
  const float* W_hh0   = (const float*)d_in[7];
  const float* b_ih0   = (const float*)d_in[8];
  const float* b_hh0   = (const float*)d_in[9];
  const float* W_ih1   = (const float*)d_in[10];
  const float* W_hh1   = (const float*)d_in[11];
  const float* b_ih1   = (const float*)d_in[12];
  const float* b_hh1   = (const float*)d_in[13];
  float* out = (float*)d_out;

  unsigned int* bar = (unsigned int*)d_ws;                 // 32 KB (slots+gen+flag)
  float* base     = (float*)((char*)d_ws + 32768);
  float* h1g      = base;                                  // 2*BH
  float* h2g      = h1g + 2 * BH;                          // 2*BH
  float* smg      = h2g + 2 * BH;                          // Bz*NK
  float* partials = smg + Bz * NK;                         // 32*512
  float* Wt       = partials + 32 * 512;                   // 512*128

  hipMemsetAsync(bar, 0, 32768, stream);
  hipLaunchKernelGGL(wt_kernel, dim3(256), dim3(256), 0, stream, W_out, Wt);

  void* ka[] = { (void*)&hiddens, (void*)&h_t, (void*)&c_t, (void*)&mask,
                 (void*)&b_out, (void*)&W_ih0, (void*)&W_hh0,
                 (void*)&b_ih0, (void*)&b_hh0, (void*)&W_ih1, (void*)&W_hh1,
                 (void*)&b_ih1, (void*)&b_hh1, (void*)&Wt, (void*)&out,
                 (void*)&h1g, (void*)&h2g, (void*)&smg, (void*)&partials,
                 (void*)&bar };
  hipError_t err = hipLaunchCooperativeKernel((void*)seq_kernel, dim3(NBLK),
                                              dim3(256), ka, 0, stream);
  if (err != hipSuccess) {
    // fallback: plain launch; 256 blocks at this occupancy are co-resident.
    hipLaunchKernelGGL(seq_kernel, dim3(NBLK), dim3(256), 0, stream,
                       hiddens, h_t, c_t, mask, b_out, W_ih0, W_hh0,
                       b_ih0, b_hh0, W_ih1, W_hh1, b_ih1, b_hh1, Wt, out,
                       h1g, h2g, smg, partials, bar);
  }
}

// Round 7
// 5986.230 us; speedup vs baseline: 5.9078x; 5.9078x over previous
//
#include <hip/hip_runtime.h>
#include <cstdint>
#include <cstddef>

// ---------------------------------------------------------------------------
// TaggingFNNDecoder round 7.
// r6 post-mortem: (1) VGPR=128 + 22.5GB WRITE => pointer arrays (40 x 64-bit)
// + staging arrays spilled to scratch; (2) FETCH 17.4GB == 70MB/step of
// L2-bypass state reads (every block read the FULL state) at ~0.5-1TB/s.
// Redesign:
//  * 128 j-groups x 2 batch-groups (4 hidden units + 16 batches per block).
//    Per-block sc-state read: 26MB/step (2.7x less).
//  * Recurrent weights LDS-resident (107KB, loaded once). Acts in REGISTERS
//    (named vf4, no arrays->no spill); weights are the only LDS operand,
//    k-sliced 16B/lane -> 4-way same-addr broadcast + 2-way banks (free).
//  * x@W_ih0 precomputed by a parallel GEMM (r1's verified xpre kernel,
//    generalized): removes x FMAs + x-weight streaming from the seq loop.
//  * 16 named accumulators; 4-stage value-halving shfl_xor butterfly
//    (bit-reverse output mapping, same scheme r6 validated for 8).
//  * Output head: P3 full W_out GEMV on 32 blocks (h2 staged to LDS first);
//    no flag, no partials, no transpose kernel.
//  * Cross-block state: r6's proven sc0-sc1 (LLC-coherent) ld/st + r4 barrier.
//  * ws_size guard: full Xpre (67.6MB) if it fits, else r1-proven 16-chunk
//    interleave (4.6MB) with c-state spill between chunks.
// ---------------------------------------------------------------------------

#define Bz   32
#define Tz   256
#define Dz   1024
#define Hz   512
#define NK   128
#define IN0  1152
#define NBLK 256
#define BH   16384      // Bz*Hz

typedef float vf4 __attribute__((ext_vector_type(4)));

__device__ __forceinline__ void ldsc4(vf4& d, const float* p) {
  asm volatile("global_load_dwordx4 %0, %1, off sc0 sc1" : "=v"(d) : "v"(p));
}
__device__ __forceinline__ void stsc1(float* p, float v) {
  asm volatile("global_store_dword %0, %1, off sc0 sc1" :: "v"(p), "v"(v) : "memory");
}
#define FENCE8(c, a0,a1,a2,a3,a4,a5,a6,a7) \
  asm volatile("s_waitcnt vmcnt(" #c ")" : "+v"(a0),"+v"(a1),"+v"(a2),"+v"(a3), \
               "+v"(a4),"+v"(a5),"+v"(a6),"+v"(a7) :: "memory")

// NOTE: macro params must not collide with vector member names x/y/z/w.
#define FMA4(acc, W_, A_) \
  acc = fmaf((W_).x,(A_).x, fmaf((W_).y,(A_).y, fmaf((W_).z,(A_).z, fmaf((W_).w,(A_).w,(acc)))))

__device__ __forceinline__ float sigf(float x) { return 1.0f / (1.0f + expf(-x)); }

// ---------------- grid barrier (r4/r6, proven) ----------------------------
__device__ __forceinline__ void gbar(unsigned int* bar, unsigned int g) {
  asm volatile("s_waitcnt vmcnt(0)" ::: "memory");
  __syncthreads();
  if (threadIdx.x == 0)
    __hip_atomic_store(bar + blockIdx.x * 16, g,
                       __ATOMIC_RELAXED, __HIP_MEMORY_SCOPE_SYSTEM);
  if (blockIdx.x == NBLK - 1) {
    unsigned int* wsl = bar + threadIdx.x * 16;
    while (__hip_atomic_load(wsl, __ATOMIC_RELAXED, __HIP_MEMORY_SCOPE_SYSTEM) < g)
      __builtin_amdgcn_s_sleep(1);
    __syncthreads();
    if (threadIdx.x == 0) {
      asm volatile("s_waitcnt vmcnt(0)" ::: "memory");
      __hip_atomic_store(bar + NBLK * 16, g,
                         __ATOMIC_RELAXED, __HIP_MEMORY_SCOPE_SYSTEM);
    }
  } else if (threadIdx.x == 0) {
    while (__hip_atomic_load(bar + NBLK * 16, __ATOMIC_RELAXED,
                             __HIP_MEMORY_SCOPE_SYSTEM) < g)
      __builtin_amdgcn_s_sleep(1);
  }
  __syncthreads();
}

// 16-row FMA over all rows r for one act vf4 from LDS base BASE at col KOFF.
#define FMAROW(r, AV, BASE, KOFF) \
  { vf4 wv = *(const vf4*)&BASE[r][KOFF]; FMA4(A##r, wv, AV); }
#define R16A(OP, AV, BASE, KOFF) \
  OP(0,AV,BASE,KOFF) OP(1,AV,BASE,KOFF) OP(2,AV,BASE,KOFF) OP(3,AV,BASE,KOFF) \
  OP(4,AV,BASE,KOFF) OP(5,AV,BASE,KOFF) OP(6,AV,BASE,KOFF) OP(7,AV,BASE,KOFF) \
  OP(8,AV,BASE,KOFF) OP(9,AV,BASE,KOFF) OP(10,AV,BASE,KOFF) OP(11,AV,BASE,KOFF) \
  OP(12,AV,BASE,KOFF) OP(13,AV,BASE,KOFF) OP(14,AV,BASE,KOFF) OP(15,AV,BASE,KOFF)

// 4-stage value-halving butterfly over 16-lane ks groups; after it, lane ks's
// A0 holds the full k-sum of row rev4(ks). (Same scheme r6 validated, rev3.)
#define RED16 { \
  { const bool hi = (ks & 1) != 0; \
    float s0=hi?A0:A8, s1=hi?A1:A9, s2=hi?A2:A10, s3=hi?A3:A11; \
    float s4=hi?A4:A12, s5=hi?A5:A13, s6=hi?A6:A14, s7=hi?A7:A15; \
    float k0=hi?A8:A0, k1=hi?A9:A1, k2=hi?A10:A2, k3=hi?A11:A3; \
    float k4=hi?A12:A4, k5=hi?A13:A5, k6=hi?A14:A6, k7=hi?A15:A7; \
    A0=k0+__shfl_xor(s0,1,64); A1=k1+__shfl_xor(s1,1,64); \
    A2=k2+__shfl_xor(s2,1,64); A3=k3+__shfl_xor(s3,1,64); \
    A4=k4+__shfl_xor(s4,1,64); A5=k5+__shfl_xor(s5,1,64); \
    A6=k6+__shfl_xor(s6,1,64); A7=k7+__shfl_xor(s7,1,64); } \
  { const bool hi = (ks & 2) != 0; \
    float s0=hi?A0:A4, s1=hi?A1:A5, s2=hi?A2:A6, s3=hi?A3:A7; \
    float k0=hi?A4:A0, k1=hi?A5:A1, k2=hi?A6:A2, k3=hi?A7:A3; \
    A0=k0+__shfl_xor(s0,2,64); A1=k1+__shfl_xor(s1,2,64); \
    A2=k2+__shfl_xor(s2,2,64); A3=k3+__shfl_xor(s3,2,64); } \
  { const bool hi = (ks & 4) != 0; \
    float s0=hi?A0:A2, s1=hi?A1:A3; float k0=hi?A2:A0, k1=hi?A3:A1; \
    A0=k0+__shfl_xor(s0,4,64); A1=k1+__shfl_xor(s1,4,64); } \
  { const bool hi = (ks & 8) != 0; \
    float s0=hi?A0:A1; float k0=hi?A1:A0; \
    A0=k0+__shfl_xor(s0,8,64); } }

#define ZERO16 A0=0.f;A1=0.f;A2=0.f;A3=0.f;A4=0.f;A5=0.f;A6=0.f;A7=0.f; \
               A8=0.f;A9=0.f;A10=0.f;A11=0.f;A12=0.f;A13=0.f;A14=0.f;A15=0.f;

// gate nonlinearity + h write. tid<64: cu=tid&3 (unit), cbl=tid>>2 (batch).
#define GATES(CREG, HDST) \
  __syncthreads(); \
  if (tid < 64) { \
    float gi = gbuf[cu][cbl],      gf = gbuf[4 + cu][cbl]; \
    float gg = gbuf[8 + cu][cbl],  go = gbuf[12 + cu][cbl]; \
    CREG = sigf(gf) * CREG + sigf(gi) * tanhf(gg); \
    stsc1(HDST + (size_t)(pg * 16 + cbl) * Hz + jg * 4 + cu, \
          sigf(go) * tanhf(CREG)); \
  }

// ---------------- output head: full W_out GEMV + softmax (one batch) ------
// src is an LDS staging of h (512 floats). t==-1: init (sm only).
__device__ void c_slot(const float* src, int t, int bb,
                       const float* __restrict__ W_out, const float* __restrict__ b_out,
                       const float* __restrict__ mask,
                       float* __restrict__ smg, float* __restrict__ out,
                       float (*cpart)[2], float* wred) {
  const int tid = threadIdx.x;
  const int n = tid & 127, kh = tid >> 7;
  float p = 0.0f;
  const float* w  = W_out + (size_t)n * Hz + kh * 256;
  const float* s2 = src + kh * 256;
  #pragma unroll 8
  for (int k = 0; k < 256; k += 4) {
    vf4 sv = *(const vf4*)(s2 + k);
    vf4 wv = *(const vf4*)(w + k);
    p += sv.x * wv.x + sv.y * wv.y + sv.z * wv.z + sv.w * wv.w;
  }
  cpart[n][kh] = p;
  __syncthreads();
  float logit = 0.0f;
  if (tid < 128) logit = cpart[n][0] + cpart[n][1] + b_out[n];
  float m = logit;
  #pragma unroll
  for (int off = 32; off >= 1; off >>= 1) m = fmaxf(m, __shfl_xor(m, off));
  if ((tid & 63) == 0 && tid < 128) wred[tid >> 6] = m;
  __syncthreads();
  float M = fmaxf(wred[0], wred[1]);
  float e = (tid < 128) ? expf(logit - M) : 0.0f;
  float s = e;
  #pragma unroll
  for (int off = 32; off >= 1; off >>= 1) s += __shfl_xor(s, off);
  if ((tid & 63) == 0 && tid < 128) wred[2 + (tid >> 6)] = s;
  __syncthreads();
  float S = wred[2] + wred[3];
  if (tid < 128) stsc1(smg + bb * NK + n, e / S);
  if (t >= 0) {
    float mk = (tid < 128) ? mask[bb * Tz + t] : 1.0f;
    float lm = (tid < 128) ? (logit + (1.0f - mk) * (-1e32f)) : -3.0e38f;
    float m2 = lm;
    #pragma unroll
    for (int off = 32; off >= 1; off >>= 1) m2 = fmaxf(m2, __shfl_xor(m2, off));
    if ((tid & 63) == 0 && tid < 128) wred[4 + (tid >> 6)] = m2;
    __syncthreads();
    float M2 = fmaxf(wred[4], wred[5]);
    float e2 = (tid < 128) ? expf(lm - M2) : 0.0f;
    float s2r = e2;
    #pragma unroll
    for (int off = 32; off >= 1; off >>= 1) s2r += __shfl_xor(s2r, off);
    if ((tid & 63) == 0 && tid < 128) wred[6 + (tid >> 6)] = s2r;
    __syncthreads();
    float S2 = wred[6] + wred[7];
    if (tid < 128) out[((size_t)bb * Tz + t) * NK + n] = e2 / S2;
  }
}

// ---------------- Xpre GEMM (r1's verified kernel, generalized) -----------
// Xpre[n][(t-t0)*32+b] = sum_k hiddens[b][t][k]*W_ih0[n][k] + b_ih0[n]+b_hh0[n]
__global__ void __launch_bounds__(256)
xpre_kernel(const float* __restrict__ hiddens, const float* __restrict__ W_ih0,
            const float* __restrict__ b_ih0, const float* __restrict__ b_hh0,
            float* __restrict__ Xpre, int t0, int colTiles, int cstride) {
  __shared__ float Ws[16][64];
  __shared__ float Hs[16][64];
  const int tid = threadIdx.x;
  const int bx = blockIdx.x % colTiles;
  const int by = blockIdx.x / colTiles;
  const int n0 = by * 64, c0 = bx * 64;
  const int tx = tid & 15, ty = tid >> 4;
  const int ldn = tid >> 2;
  const int ldk = (tid & 3) * 4;

  const int bb = ldn & 31;
  const int tt = t0 + (c0 >> 5) + (ldn >> 5);
  const float* hsrc = hiddens + ((size_t)bb * Tz + tt) * Dz + ldk;
  const float* wsrc = W_ih0 + (size_t)(n0 + ldn) * IN0 + ldk;

  float acc[4][4] = {};
  vf4 wv = *(const vf4*)(wsrc);
  vf4 hv = *(const vf4*)(hsrc);
  for (int k0 = 0; k0 < Dz; k0 += 16) {
    __syncthreads();
    Ws[ldk + 0][ldn] = wv.x; Ws[ldk + 1][ldn] = wv.y;
    Ws[ldk + 2][ldn] = wv.z; Ws[ldk + 3][ldn] = wv.w;
    Hs[ldk + 0][ldn] = hv.x; Hs[ldk + 1][ldn] = hv.y;
    Hs[ldk + 2][ldn] = hv.z; Hs[ldk + 3][ldn] = hv.w;
    __syncthreads();
    if (k0 + 16 < Dz) {
      wv = *(const vf4*)(wsrc + k0 + 16);
      hv = *(const vf4*)(hsrc + k0 + 16);
    }
    #pragma unroll
    for (int k = 0; k < 16; ++k) {
      vf4 a4 = *(const vf4*)&Ws[k][ty * 4];
      vf4 b4 = *(const vf4*)&Hs[k][tx * 4];
      acc[0][0] += a4.x * b4.x; acc[0][1] += a4.x * b4.y; acc[0][2] += a4.x * b4.z; acc[0][3] += a4.x * b4.w;
      acc[1][0] += a4.y * b4.x; acc[1][1] += a4.y * b4.y; acc[1][2] += a4.y * b4.z; acc[1][3] += a4.y * b4.w;
      acc[2][0] += a4.z * b4.x; acc[2][1] += a4.z * b4.y; acc[2][2] += a4.z * b4.z; acc[2][3] += a4.z * b4.w;
      acc[3][0] += a4.w * b4.x; acc[3][1] += a4.w * b4.y; acc[3][2] += a4.w * b4.z; acc[3][3] += a4.w * b4.w;
    }
  }
  #pragma unroll
  for (int i = 0; i < 4; ++i) {
    int n = n0 + ty * 4 + i;
    float bi = b_ih0[n] + b_hh0[n];
    vf4 v; v.x = acc[i][0] + bi; v.y = acc[i][1] + bi;
    v.z = acc[i][2] + bi; v.w = acc[i][3] + bi;
    *(vf4*)(Xpre + (size_t)n * cstride + c0 + tx * 4) = v;
  }
}

// ---------------- the persistent kernel -----------------------------------
__global__ void __launch_bounds__(256)
seq_kernel(const float* __restrict__ hiddens,
           const float* __restrict__ h_t, const float* __restrict__ c_t,
           const float* __restrict__ mask,
           const float* __restrict__ W_out, const float* __restrict__ b_out,
           const float* __restrict__ W_ih0, const float* __restrict__ W_hh0,
           const float* __restrict__ W_ih1, const float* __restrict__ W_hh1,
           const float* __restrict__ b_ih1, const float* __restrict__ b_hh1,
           const float* __restrict__ Xpre, float* __restrict__ out,
           float* __restrict__ h1g, float* __restrict__ h2g,
           float* __restrict__ smg, float* __restrict__ c1g, float* __restrict__ c2g,
           unsigned int* bar, int t0, int nsteps, int cstride) {
  __shared__ float wA[16][640];     // [W_hh0(512) | W_ih0 sm-cols(128)]
  __shared__ float wB[16][1024];    // [W_ih1(512) | W_hh1(512)]
  __shared__ float gbuf[16][17];
  __shared__ float biasB[16];
  __shared__ float hsg[512];
  __shared__ float cpart[128][2];
  __shared__ float wred[8];

  const int tid = threadIdx.x;
  const int bid = blockIdx.x;
  const int jg  = bid >> 1;          // j-group 0..127 (4 hidden units)
  const int pg  = bid & 1;           // batch-group 0..1 (16 batches)
  const int ks  = tid & 15;          // k-slice 0..15
  const int bbl = tid >> 4;          // local batch 0..15
  const int bbg = pg * 16 + bbl;     // global batch
  const int ks4 = ks * 4;
  const int cu  = tid & 3, cbl = tid >> 2;   // GATES mapping (tid<64)
  const int rr  = ((ks & 1) << 3) | ((ks & 2) << 1) | ((ks & 4) >> 1) | ((ks & 8) >> 3);
  const int rowG = ((rr >> 2) * Hz) + jg * 4 + (rr & 3);   // butterfly-out row

  // ---- one-time: weights -> LDS (block-private rows, read-only source) ----
  for (int r = 0; r < 16; ++r) {
    const int row = ((r >> 2) * Hz) + jg * 4 + (r & 3);
    if (tid * 4 < 512)
      *(vf4*)&wA[r][tid * 4] = *(const vf4*)(W_hh0 + (size_t)row * Hz + tid * 4);
    if (tid * 4 < 128)
      *(vf4*)&wA[r][512 + tid * 4] = *(const vf4*)(W_ih0 + (size_t)row * IN0 + 1024 + tid * 4);
    if (tid * 4 < 512) {
      *(vf4*)&wB[r][tid * 4]       = *(const vf4*)(W_ih1 + (size_t)row * Hz + tid * 4);
      *(vf4*)&wB[r][512 + tid * 4] = *(const vf4*)(W_hh1 + (size_t)row * Hz + tid * 4);
    }
  }
  if (tid < 16) {
    const int row = ((tid >> 2) * Hz) + jg * 4 + (tid & 3);
    biasB[tid] = b_ih1[row] + b_hh1[row];
  }

  // ---- c-state in registers (tid<64: unit cu, batch cbl) ----
  float c1r = 0.0f, c2r = 0.0f;
  if (tid < 64) {
    const size_t ci = (size_t)(pg * 16 + cbl) * Hz + jg * 4 + cu;
    if (t0 == 0) { c1r = c_t[ci]; c2r = c_t[BH + ci]; }
    else         { c1r = c1g[ci]; c2r = c2g[ci]; }
  }

  if (t0 == 0) {
    // stage h_t into parity-1 h buffers; compute sm(-1)
    if (bid < 32 && tid < 128) {
      vf4 v1 = *(const vf4*)(h_t + (size_t)bid * Hz + tid * 4);
      vf4 v2 = *(const vf4*)(h_t + BH + (size_t)bid * Hz + tid * 4);
      float* d1 = h1g + BH + (size_t)bid * Hz + tid * 4;
      float* d2 = h2g + BH + (size_t)bid * Hz + tid * 4;
      stsc1(d1, v1.x); stsc1(d1 + 1, v1.y); stsc1(d1 + 2, v1.z); stsc1(d1 + 3, v1.w);
      stsc1(d2, v2.x); stsc1(d2 + 1, v2.y); stsc1(d2 + 2, v2.z); stsc1(d2 + 3, v2.w);
    }
    if (bid < 32) {
      if (tid < 128)
        *(vf4*)&hsg[tid * 4] = *(const vf4*)(hiddens + (size_t)bid * Tz * Dz + tid * 4);
      __syncthreads();
      c_slot(hsg, -1, bid, W_out, b_out, mask, smg, out, cpart, wred);
    }
  }
  __syncthreads();
  unsigned int g = 1;
  gbar(bar, g); ++g;

  for (int t = t0; t < t0 + nsteps; ++t) {
    const float* h1prev = h1g + ((t + 1) & 1) * BH;
    float*       h1cur  = h1g + (t & 1) * BH;
    const float* h2prev = h2g + ((t + 1) & 1) * BH;
    float*       h2cur  = h2g + (t & 1) * BH;
    float A0,A1,A2,A3,A4,A5,A6,A7,A8,A9,A10,A11,A12,A13,A14,A15;

    // ============ P1: layer-0 gates over [h1prev(512) | sm(128)] ==========
    {
      vf4 ah0,ah1,ah2,ah3,ah4,ah5,ah6,ah7, as0,as1;
      const float* hp = h1prev + (size_t)bbg * Hz + ks4;
      ldsc4(ah0, hp);        ldsc4(ah1, hp + 64);  ldsc4(ah2, hp + 128);
      ldsc4(ah3, hp + 192);  ldsc4(ah4, hp + 256); ldsc4(ah5, hp + 320);
      ldsc4(ah6, hp + 384);  ldsc4(ah7, hp + 448);
      const float* sp = smg + (size_t)bbg * NK + ks4;
      ldsc4(as0, sp);        ldsc4(as1, sp + 64);
      float xv = Xpre[(size_t)rowG * cstride + (t - t0) * 32 + bbg];  // cached
      ZERO16
      FENCE8(3, ah0,ah1,ah2,ah3,ah4,ah5,ah6,ah7);
      R16A(FMAROW, ah0, wA, ks4 +   0)
      R16A(FMAROW, ah1, wA, ks4 +  64)
      R16A(FMAROW, ah2, wA, ks4 + 128)
      R16A(FMAROW, ah3, wA, ks4 + 192)
      R16A(FMAROW, ah4, wA, ks4 + 256)
      R16A(FMAROW, ah5, wA, ks4 + 320)
      R16A(FMAROW, ah6, wA, ks4 + 384)
      R16A(FMAROW, ah7, wA, ks4 + 448)
      asm volatile("s_waitcnt vmcnt(0)" : "+v"(as0), "+v"(as1), "+v"(xv) :: "memory");
      R16A(FMAROW, as0, wA, ks4 + 512)
      R16A(FMAROW, as1, wA, ks4 + 576)
      RED16
      gbuf[rr][bbl] = A0 + xv;          // Xpre already includes both biases
      GATES(c1r, h1cur)
    }
    gbar(bar, g); ++g;

    // ============ P2: layer-1 gates over [h1cur(512) | h2prev(512)] =======
    {
      vf4 aa0,aa1,aa2,aa3,aa4,aa5,aa6,aa7, ab0,ab1,ab2,ab3,ab4,ab5,ab6,ab7;
      const float* p1 = h1cur + (size_t)bbg * Hz + ks4;
      ldsc4(aa0, p1);       ldsc4(aa1, p1 + 64);  ldsc4(aa2, p1 + 128);
      ldsc4(aa3, p1 + 192); ldsc4(aa4, p1 + 256); ldsc4(aa5, p1 + 320);
      ldsc4(aa6, p1 + 384); ldsc4(aa7, p1 + 448);
      const float* p2 = h2prev + (size_t)bbg * Hz + ks4;
      ldsc4(ab0, p2);       ldsc4(ab1, p2 + 64);  ldsc4(ab2, p2 + 128);
      ldsc4(ab3, p2 + 192); ldsc4(ab4, p2 + 256); ldsc4(ab5, p2 + 320);
      ldsc4(ab6, p2 + 384); ldsc4(ab7, p2 + 448);
      ZERO16
      FENCE8(8, aa0,aa1,aa2,aa3,aa4,aa5,aa6,aa7);
      R16A(FMAROW, aa0, wB, ks4 +   0)
      R16A(FMAROW, aa1, wB, ks4 +  64)
      R16A(FMAROW, aa2, wB, ks4 + 128)
      R16A(FMAROW, aa3, wB, ks4 + 192)
      R16A(FMAROW, aa4, wB, ks4 + 256)
      R16A(FMAROW, aa5, wB, ks4 + 320)
      R16A(FMAROW, aa6, wB, ks4 + 384)
      R16A(FMAROW, aa7, wB, ks4 + 448)
      FENCE8(0, ab0,ab1,ab2,ab3,ab4,ab5,ab6,ab7);
      R16A(FMAROW, ab0, wB, ks4 + 512)
      R16A(FMAROW, ab1, wB, ks4 + 576)
      R16A(FMAROW, ab2, wB, ks4 + 640)
      R16A(FMAROW, ab3, wB, ks4 + 704)
      R16A(FMAROW, ab4, wB, ks4 + 768)
      R16A(FMAROW, ab5, wB, ks4 + 832)
      R16A(FMAROW, ab6, wB, ks4 + 896)
      R16A(FMAROW, ab7, wB, ks4 + 960)
      RED16
      gbuf[rr][bbl] = A0 + biasB[rr];
      GATES(c2r, h2cur)
    }
    gbar(bar, g); ++g;

    // ============ P3: output head (blocks 0..31, batch = bid) =============
    if (bid < 32) {
      if (tid < 128) {
        vf4 v;
        ldsc4(v, h2cur + (size_t)bid * Hz + tid * 4);
        asm volatile("s_waitcnt vmcnt(0)" : "+v"(v) :: "memory");
        *(vf4*)&hsg[tid * 4] = v;
      }
      __syncthreads();
      c_slot(hsg, t, bid, W_out, b_out, mask, smg, out, cpart, wred);
    }
    gbar(bar, g); ++g;
  }

  // spill c-state for next chunk (no-op cost in full path)
  if (tid < 64) {
    const size_t ci = (size_t)(pg * 16 + cbl) * Hz + jg * 4 + cu;
    stsc1(c1g + ci, c1r);
    stsc1(c2g + ci, c2r);
  }
}

// ---------------------------------------------------------------------------
extern "C" void kernel_launch(void* const* d_in, const int* in_sizes, int n_in,
                              void* d_out, int out_size, void* d_ws, size_t ws_size,
                              hipStream_t stream) {
  (void)in_sizes; (void)n_in; (void)out_size;
  const float* hiddens = (const float*)d_in[0];
  const float* h_t     = (const float*)d_in[1];
  const float* c_t     = (const float*)d_in[2];
  const float* mask    = (const float*)d_in[3];
  const float* W_out   = (const float*)d_in[4];
  const float* b_out   = (const float*)d_in[5];
  const float* W_ih0   = (const float*)d_in[6];
  const float* W_hh0   = (const float*)d_in[7];
  const float* b_ih0   = (const float*)d_in[8];
  const float* b_hh0   = (const float*)d_in[9];
  const float* W_ih1   = (const float*)d_in[10];
  const float* W_hh1   = (const float*)d_in[11];
  const float* b_ih1   = (const float*)d_in[12];
  const float* b_hh1   = (const float*)d_in[13];
  float* out = (float*)d_out;

  unsigned int* bar = (unsigned int*)d_ws;                 // 32 KB
  float* base = (float*)((char*)d_ws + 32768);
  float* h1g  = base;                                      // 2*BH
  float* h2g  = h1g + 2 * BH;                              // 2*BH
  float* smg  = h2g + 2 * BH;                              // Bz*NK
  float* c1g  = smg + Bz * NK;                             // BH
  float* c2g  = c1g + BH;                                  // BH
  float* Xpre = c2g + BH;                                  // full: 2048*8192

  const size_t fullNeed = 32768 + (size_t)(102400 + 2048 * 8192) * 4;
  const bool full = ws_size >= fullNeed;
  const int NCH    = full ? 1 : 16;
  const int CH     = full ? Tz : 16;
  const int cstr   = full ? (Tz * 32) : (16 * 32);
  const int cTiles = cstr / 64;

  for (int c = 0; c < NCH; ++c) {
    const int t0 = c * CH;
    hipMemsetAsync(bar, 0, 32768, stream);
    hipLaunchKernelGGL(xpre_kernel, dim3(32 * cTiles), dim3(256), 0, stream,
                       hiddens, W_ih0, b_ih0, b_hh0, Xpre, t0, cTiles, cstr);
    int nsteps = CH, cs = cstr, tt0 = t0;
    void* ka[] = { (void*)&hiddens, (void*)&h_t, (void*)&c_t, (void*)&mask,
                   (void*)&W_out, (void*)&b_out, (void*)&W_ih0, (void*)&W_hh0,
                   (void*)&W_ih1, (void*)&W_hh1, (void*)&b_ih1, (void*)&b_hh1,
                   (void*)&Xpre, (void*)&out, (void*)&h1g, (void*)&h2g,
                   (void*)&smg, (void*)&c1g, (void*)&c2g, (void*)&bar,
                   (void*)&tt0, (void*)&nsteps, (void*)&cs };
    hipError_t err = hipLaunchCooperativeKernel((void*)seq_kernel, dim3(NBLK),
                                                dim3(256), ka, 0, stream);
    if (err != hipSuccess) {
      // fallback: plain launch; 256 blocks at 1 block/CU are co-resident.
      hipLaunchKernelGGL(seq_kernel, dim3(NBLK), dim3(256), 0, stream,
                         hiddens, h_t, c_t, mask, W_out, b_out, W_ih0, W_hh0,
                         W_ih1, W_hh1, b_ih1, b_hh1, Xpre, out,
                         h1g, h2g, smg, c1g, c2g, bar, tt0, nsteps, cs);
    }
  }
}